// Round 1
// baseline (1781.175 us; speedup 1.0000x reference)
//
#include <hip/hip_runtime.h>
#include <math.h>

#define N_TOK 2000
#define C_DIM 256
#define NH 8
#define HD 32
#define SCALE 25.0f
#define SIM_TH 0.75f
#define EPSF 1e-8f

// ---------------------------------------------------------------------------
// Kernel 1: QKV projection (per-row GEMM) fused with l2-normalization and
// scatter into [H][N][HD] layouts.
// grid = (N_TOK, 2)  [y: 0=cls, 1=reg], block = 256
// ---------------------------------------------------------------------------
__global__ __launch_bounds__(256) void qkv_norm_kernel(
    const float* __restrict__ x_cls, const float* __restrict__ x_reg,
    const float* __restrict__ W_cls, const float* __restrict__ W_reg,
    float* __restrict__ qn_cls, float* __restrict__ kn_cls,
    float* __restrict__ qn_reg, float* __restrict__ kn_reg,
    float* __restrict__ v_cls,  float* __restrict__ vn_cls) {
  __shared__ float xs[C_DIM];
  __shared__ float res[768];
  __shared__ float inv_norm[24];

  const int n = blockIdx.x;
  const int which = blockIdx.y;  // 0 = cls, 1 = reg
  const int tid = threadIdx.x;

  const float* __restrict__ x = which ? x_reg : x_cls;
  const float* __restrict__ W = which ? W_reg : W_cls;

  xs[tid] = x[n * C_DIM + tid];
  __syncthreads();

  // each thread computes 3 output columns: tid, tid+256, tid+512
  float acc0 = 0.f, acc1 = 0.f, acc2 = 0.f;
  const int c0 = tid, c1 = tid + 256, c2 = tid + 512;
#pragma unroll 4
  for (int k = 0; k < C_DIM; k++) {
    const float xv = xs[k];
    const float* __restrict__ wr = W + k * 768;
    acc0 += xv * wr[c0];
    acc1 += xv * wr[c1];
    acc2 += xv * wr[c2];
  }
  res[c0] = acc0;
  res[c1] = acc1;
  res[c2] = acc2;
  __syncthreads();

  // 24 groups of 32 (3 qkv * 8 heads): inverse norms
  if (tid < 24) {
    float ss = 0.f;
#pragma unroll
    for (int d = 0; d < HD; d++) {
      const float v = res[tid * HD + d];
      ss += v * v;
    }
    inv_norm[tid] = 1.0f / (sqrtf(ss) + EPSF);
  }
  __syncthreads();

  // scatter: c = qkv*256 + h*32 + d  ->  buf[h][n][d]
#pragma unroll
  for (int j = 0; j < 3; j++) {
    const int c = tid + j * 256;
    const int grp = c >> 5;        // 0..23
    const int qkv_idx = c >> 8;    // 0,1,2
    const int h = (c >> 5) & 7;
    const int d = c & 31;
    const float val = res[c];
    const float nval = val * inv_norm[grp];
    const int row = (h * N_TOK + n) * HD + d;
    if (which == 0) {
      if (qkv_idx == 0)      qn_cls[row] = nval;
      else if (qkv_idx == 1) kn_cls[row] = nval;
      else { v_cls[row] = val; vn_cls[row] = nval; }
    } else {
      if (qkv_idx == 0)      qn_reg[row] = nval;
      else if (qkv_idx == 1) kn_reg[row] = nval;
      // v_reg is unused by the reference
    }
  }
}

// ---------------------------------------------------------------------------
// Block-wide reductions for 256 threads (4 waves of 64)
// ---------------------------------------------------------------------------
__device__ __forceinline__ float block_max256(float v, float* red) {
#pragma unroll
  for (int off = 32; off > 0; off >>= 1) v = fmaxf(v, __shfl_xor(v, off, 64));
  __syncthreads();  // protect red from any previous use
  if ((threadIdx.x & 63) == 0) red[threadIdx.x >> 6] = v;
  __syncthreads();
  return fmaxf(fmaxf(red[0], red[1]), fmaxf(red[2], red[3]));
}

__device__ __forceinline__ float block_sum256(float v, float* red) {
#pragma unroll
  for (int off = 32; off > 0; off >>= 1) v += __shfl_xor(v, off, 64);
  __syncthreads();
  if ((threadIdx.x & 63) == 0) red[threadIdx.x >> 6] = v;
  __syncthreads();
  return (red[0] + red[1]) + (red[2] + red[3]);
}

// ---------------------------------------------------------------------------
// Kernel 2: one block per query row i. Loops heads; computes score rows,
// softmaxes, mask, attn@V, accumulates sim/raw rows; then sim_round2 epilogue.
// grid = N_TOK, block = 256
// ---------------------------------------------------------------------------
__global__ __launch_bounds__(256) void attn_row_kernel(
    const float* __restrict__ qn_cls, const float* __restrict__ kn_cls,
    const float* __restrict__ qn_reg, const float* __restrict__ kn_reg,
    const float* __restrict__ v_cls,  const float* __restrict__ vn_cls,
    float* __restrict__ out_x, float* __restrict__ out_sim) {
  __shared__ float s_cls[N_TOK];
  __shared__ float s_reg[N_TOK];
  __shared__ float sim_row[N_TOK];
  __shared__ float raw_row[N_TOK];
  __shared__ float qc_s[HD], qr_s[HD], vi_s[HD];
  __shared__ float part[8][HD];
  __shared__ float red[4];

  const int i = blockIdx.x;
  const int tid = threadIdx.x;
  const int bstart = (i / 10) * 10;

  for (int m = tid; m < N_TOK; m += 256) {
    sim_row[m] = 0.f;
    raw_row[m] = 0.f;
  }
  __syncthreads();

  for (int h = 0; h < NH; h++) {
    if (tid < HD) {
      qc_s[tid] = qn_cls[(h * N_TOK + i) * HD + tid];
      qr_s[tid] = qn_reg[(h * N_TOK + i) * HD + tid];
      vi_s[tid] = vn_cls[(h * N_TOK + i) * HD + tid];
    }
    __syncthreads();

    // pass 1: score rows (dot over hd=32, float4-vectorized)
    float lmax_c = -1e30f, lmax_r = -1e30f;
    for (int m = tid; m < N_TOK; m += 256) {
      const float4* __restrict__ kc4 =
          (const float4*)(kn_cls + (size_t)(h * N_TOK + m) * HD);
      const float4* __restrict__ kr4 =
          (const float4*)(kn_reg + (size_t)(h * N_TOK + m) * HD);
      const float4* __restrict__ vm4 =
          (const float4*)(vn_cls + (size_t)(h * N_TOK + m) * HD);
      float dc = 0.f, dr = 0.f, dv = 0.f;
#pragma unroll
      for (int j = 0; j < 8; j++) {
        const float4 a = kc4[j];
        dc += qc_s[4 * j] * a.x + qc_s[4 * j + 1] * a.y +
              qc_s[4 * j + 2] * a.z + qc_s[4 * j + 3] * a.w;
        const float4 b = kr4[j];
        dr += qr_s[4 * j] * b.x + qr_s[4 * j + 1] * b.y +
              qr_s[4 * j + 2] * b.z + qr_s[4 * j + 3] * b.w;
        const float4 c = vm4[j];
        dv += vi_s[4 * j] * c.x + vi_s[4 * j + 1] * c.y +
              vi_s[4 * j + 2] * c.z + vi_s[4 * j + 3] * c.w;
      }
      dc *= SCALE;
      dr *= SCALE;
      s_cls[m] = dc;
      s_reg[m] = dr;
      raw_row[m] += dv;
      lmax_c = fmaxf(lmax_c, dc);
      lmax_r = fmaxf(lmax_r, dr);
    }

    const float mc = block_max256(lmax_c, red);
    const float mr = block_max256(lmax_r, red);

    // exp + sums (each thread touches only its own m slots)
    float lsum_c = 0.f, lsum_r = 0.f;
    for (int m = tid; m < N_TOK; m += 256) {
      const float ec = expf(s_cls[m] - mc);
      const float er = expf(s_reg[m] - mr);
      s_cls[m] = ec;
      s_reg[m] = er;
      lsum_c += ec;
      lsum_r += er;
    }
    const float sc = block_sum256(lsum_c, red);
    const float sr = block_sum256(lsum_r, red);
    const float inv_c = 1.0f / sc, inv_r = 1.0f / sr;

    // attn = avg of softmaxes, block-diag mask, accumulate sim
    for (int m = tid; m < N_TOK; m += 256) {
      float a = 0.5f * (s_cls[m] * inv_c + s_reg[m] * inv_r);
      if (m >= bstart && m < bstart + 9 && m != i) a = 0.f;
      s_cls[m] = a;  // reuse as attn row
      sim_row[m] += a;
    }
    __syncthreads();

    // x[i][h*32+d] = sum_m attn[m] * v_cls[h][m][d]
    const int d = tid & 31;
    const int slice = tid >> 5;  // 8 slices of 250 columns
    const int m0 = slice * 250;
    float acc = 0.f;
    for (int m = m0; m < m0 + 250; m++) {
      acc += s_cls[m] * v_cls[(size_t)(h * N_TOK + m) * HD + d];
    }
    part[slice][d] = acc;
    __syncthreads();
    if (tid < HD) {
      float xv = 0.f;
#pragma unroll
      for (int s = 0; s < 8; s++) xv += part[s][tid];
      out_x[i * 512 + h * HD + tid] = xv;                               // x
      out_x[i * 512 + 256 + h * HD + tid] =
          v_cls[(size_t)(h * N_TOK + i) * HD + tid];                    // x_ori
    }
    __syncthreads();
  }

  // ---- sim_round2 epilogue ----
  float lm = -1e30f;
  for (int m = tid; m < N_TOK; m += 256) {
    const float s = sim_row[m] * 0.125f;  // /num_heads
    sim_row[m] = s;
    lm = fmaxf(lm, s);
  }
  const float M = block_max256(lm, red);

  float ls = 0.f;
  for (int m = tid; m < N_TOK; m += 256) {
    const float e = expf(sim_row[m] - M);
    sim_row[m] = e;
    ls += e;
  }
  const float S = block_sum256(ls, red);
  const float invS = 1.0f / S;

  float lms = 0.f;
  for (int m = tid; m < N_TOK; m += 256) {
    const float p = sim_row[m] * invS;
    const float mask = (raw_row[m] * 0.125f > SIM_TH) ? 1.f : 0.f;
    const float mp = mask * p;
    sim_row[m] = mp;
    lms += mp;
  }
  const float MS = block_sum256(lms, red);
  const float invMS = 1.0f / (MS + EPSF);

  for (int m = tid; m < N_TOK; m += 256) {
    out_sim[(size_t)i * N_TOK + m] = sim_row[m] * invMS;
  }
}

// ---------------------------------------------------------------------------
extern "C" void kernel_launch(void* const* d_in, const int* in_sizes, int n_in,
                              void* d_out, int out_size, void* d_ws,
                              size_t ws_size, hipStream_t stream) {
  const float* x_cls = (const float*)d_in[0];
  const float* x_reg = (const float*)d_in[1];
  const float* W_cls = (const float*)d_in[2];
  const float* W_reg = (const float*)d_in[3];

  // workspace layout: six [H][N][HD] fp32 buffers = 6 * 512000 floats (12.3 MB)
  float* ws = (float*)d_ws;
  const size_t seg = (size_t)NH * N_TOK * HD;
  float* qn_cls = ws;
  float* kn_cls = qn_cls + seg;
  float* qn_reg = kn_cls + seg;
  float* kn_reg = qn_reg + seg;
  float* v_cls  = kn_reg + seg;
  float* vn_cls = v_cls + seg;

  dim3 g1(N_TOK, 2);
  qkv_norm_kernel<<<g1, 256, 0, stream>>>(x_cls, x_reg, W_cls, W_reg, qn_cls,
                                          kn_cls, qn_reg, kn_reg, v_cls,
                                          vn_cls);

  float* out_x = (float*)d_out;                 // [2000, 512]
  float* out_sim = out_x + (size_t)N_TOK * 512; // [2000, 2000]
  attn_row_kernel<<<N_TOK, 256, 0, stream>>>(qn_cls, kn_cls, qn_reg, kn_reg,
                                             v_cls, vn_cls, out_x, out_sim);
}

// Round 2
// 1528.678 us; speedup vs baseline: 1.1652x; 1.1652x over previous
//
#include <hip/hip_runtime.h>
#include <math.h>

#define N_TOK 2000
#define NH 8
#define HD 32
#define SCALE 25.0f
#define SIM_TH 0.75f
#define EPSF 1e-8f
#define NSLOT 8  // ceil(2000/256)

// force a uniform value into an SGPR so dot-loop FMAs are v_fmac(v, s, v)
__device__ __forceinline__ float rfl(float x) {
  return __int_as_float(__builtin_amdgcn_readfirstlane(__float_as_int(x)));
}

__device__ __forceinline__ float block_max256(float v, float* red) {
#pragma unroll
  for (int off = 32; off > 0; off >>= 1) v = fmaxf(v, __shfl_xor(v, off, 64));
  __syncthreads();
  if ((threadIdx.x & 63) == 0) red[threadIdx.x >> 6] = v;
  __syncthreads();
  return fmaxf(fmaxf(red[0], red[1]), fmaxf(red[2], red[3]));
}
__device__ __forceinline__ float block_sum256(float v, float* red) {
#pragma unroll
  for (int off = 32; off > 0; off >>= 1) v += __shfl_xor(v, off, 64);
  __syncthreads();
  if ((threadIdx.x & 63) == 0) red[threadIdx.x >> 6] = v;
  __syncthreads();
  return (red[0] + red[1]) + (red[2] + red[3]);
}

// ---------------------------------------------------------------------------
// Kernel 1: QKV projection + l2norm. 4 rows per block (W re-read /4).
// Outputs: qn_cls/qn_reg row-major [h][n][32];
//          kct/krt/vnt transposed [h][g=d/4][m] float4-component layout;
//          v_rm row-major [h][n][32].
// grid = (500, 2), block = 256
// ---------------------------------------------------------------------------
__global__ __launch_bounds__(256) void qkv_norm_kernel(
    const float* __restrict__ x_cls, const float* __restrict__ x_reg,
    const float* __restrict__ W_cls, const float* __restrict__ W_reg,
    float* __restrict__ qn_cls, float* __restrict__ qn_reg,
    float* __restrict__ kct, float* __restrict__ krt,
    float* __restrict__ vnt, float* __restrict__ v_rm) {
  __shared__ float xs[4][256];
  __shared__ float res[4][768];
  __shared__ float inv_norm[96];

  const int n0 = blockIdx.x * 4;
  const int which = blockIdx.y;
  const int tid = threadIdx.x;
  const float* __restrict__ x = which ? x_reg : x_cls;
  const float* __restrict__ W = which ? W_reg : W_cls;

#pragma unroll
  for (int r = 0; r < 4; r++) xs[r][tid] = x[(n0 + r) * 256 + tid];
  __syncthreads();

  float acc[4][3];
#pragma unroll
  for (int r = 0; r < 4; r++) acc[r][0] = acc[r][1] = acc[r][2] = 0.f;

  for (int k = 0; k < 256; k++) {
    const float* __restrict__ wr = W + k * 768;
    const float w0 = wr[tid], w1 = wr[tid + 256], w2 = wr[tid + 512];
#pragma unroll
    for (int r = 0; r < 4; r++) {
      const float xv = xs[r][k];
      acc[r][0] += xv * w0;
      acc[r][1] += xv * w1;
      acc[r][2] += xv * w2;
    }
  }
#pragma unroll
  for (int r = 0; r < 4; r++) {
    res[r][tid] = acc[r][0];
    res[r][tid + 256] = acc[r][1];
    res[r][tid + 512] = acc[r][2];
  }
  __syncthreads();

  if (tid < 96) {
    const int r = tid / 24, grp = tid % 24;
    float ss = 0.f;
#pragma unroll
    for (int d = 0; d < HD; d++) {
      const float v = res[r][grp * 32 + d];
      ss += v * v;
    }
    inv_norm[tid] = 1.0f / (sqrtf(ss) + EPSF);
  }
  __syncthreads();

#pragma unroll
  for (int j = 0; j < 3; j++) {
    const int c = tid + j * 256;
    const int qkv = c >> 8, grp = c >> 5;
    const int h = grp & 7, d = c & 31;
    const int g = d >> 2, comp = d & 3;
#pragma unroll
    for (int r = 0; r < 4; r++) {
      const int n = n0 + r;
      const float val = res[r][c];
      const float nval = val * inv_norm[r * 24 + grp];
      if (qkv == 0) {
        (which ? qn_reg : qn_cls)[(h * N_TOK + n) * HD + d] = nval;
      } else if (qkv == 1) {
        (which ? krt : kct)[((h * 8 + g) * N_TOK + n) * 4 + comp] = nval;
      } else if (which == 0) {
        v_rm[(h * N_TOK + n) * HD + d] = val;
        vnt[((h * 8 + g) * N_TOK + n) * 4 + comp] = nval;
      }
    }
  }
}

// ---------------------------------------------------------------------------
// Kernel 2: 2 query rows per block; q in SGPRs; transposed-coalesced K loads.
// grid = 1000, block = 256. LDS ~56KB -> 2 blocks/CU.
// ---------------------------------------------------------------------------
__global__ __launch_bounds__(256) void attn2_kernel(
    const float* __restrict__ qn_cls, const float* __restrict__ qn_reg,
    const float* __restrict__ kct, const float* __restrict__ krt,
    const float* __restrict__ vnt, const float* __restrict__ v_rm,
    float* __restrict__ out_x, float* __restrict__ out_sim) {
  __shared__ float s_attn[2 * N_TOK];
  __shared__ float sim_row[2 * N_TOK];
  __shared__ float raw_row[2 * N_TOK];
  __shared__ float4 part4[32][2][8];
  __shared__ float red[4];

  const int tid = threadIdx.x;
  const int i0 = blockIdx.x * 2;
  const int i1 = i0 + 1;
  const int b0 = (i0 / 10) * 10;
  const int b1 = (i1 / 10) * 10;

  for (int m = tid; m < 2 * N_TOK; m += 256) {
    sim_row[m] = 0.f;
    raw_row[m] = 0.f;
  }
  __syncthreads();

  float q0[HD], q1[HD];   // uniform (SGPR-resident)
  float sc0[NSLOT], sc1[NSLOT];

  for (int h = 0; h < NH; h++) {
    // ================= phase C: cls scores =================
    {
      const float* __restrict__ p0 = qn_cls + (size_t)(h * N_TOK + i0) * HD;
      const float* __restrict__ p1 = qn_cls + (size_t)(h * N_TOK + i1) * HD;
#pragma unroll
      for (int d = 0; d < HD; d++) {
        q0[d] = rfl(p0[d]);
        q1[d] = rfl(p1[d]);
      }
    }
    float lm0 = -1e30f, lm1 = -1e30f;
    {
      const float4* __restrict__ kt4 =
          (const float4*)kct + (size_t)h * 8 * N_TOK;
      for (int t = 0; t < NSLOT; t++) {
        const int m = tid + 256 * t;
        const int mc = (m < N_TOK) ? m : (N_TOK - 1);
        float4 kv[8];
#pragma unroll
        for (int g = 0; g < 8; g++) kv[g] = kt4[g * N_TOK + mc];
        float d0 = 0.f, d1 = 0.f;
#pragma unroll
        for (int g = 0; g < 8; g++) {
          d0 += q0[4 * g] * kv[g].x + q0[4 * g + 1] * kv[g].y +
                q0[4 * g + 2] * kv[g].z + q0[4 * g + 3] * kv[g].w;
          d1 += q1[4 * g] * kv[g].x + q1[4 * g + 1] * kv[g].y +
                q1[4 * g + 2] * kv[g].z + q1[4 * g + 3] * kv[g].w;
        }
        d0 *= SCALE;
        d1 *= SCALE;
        if (m >= N_TOK) { d0 = -1e30f; d1 = -1e30f; }
        sc0[t] = d0;
        sc1[t] = d1;
        lm0 = fmaxf(lm0, d0);
        lm1 = fmaxf(lm1, d1);
      }
    }
    const float M0c = block_max256(lm0, red);
    const float M1c = block_max256(lm1, red);
    float ls0 = 0.f, ls1 = 0.f;
#pragma unroll
    for (int t = 0; t < NSLOT; t++) {
      const float e0 = expf(sc0[t] - M0c);
      const float e1 = expf(sc1[t] - M1c);
      sc0[t] = e0;
      sc1[t] = e1;
      ls0 += e0;
      ls1 += e1;
    }
    const float S0c = block_sum256(ls0, red);
    const float S1c = block_sum256(ls1, red);
    const float n0c = 0.5f / S0c, n1c = 0.5f / S1c;
#pragma unroll
    for (int t = 0; t < NSLOT; t++) {
      const int m = tid + 256 * t;
      if (m < N_TOK) {
        s_attn[m] = sc0[t] * n0c;
        s_attn[N_TOK + m] = sc1[t] * n1c;
      }
    }

    // ================= phase R: reg scores + combine + mask + sim ==========
    {
      const float* __restrict__ p0 = qn_reg + (size_t)(h * N_TOK + i0) * HD;
      const float* __restrict__ p1 = qn_reg + (size_t)(h * N_TOK + i1) * HD;
#pragma unroll
      for (int d = 0; d < HD; d++) {
        q0[d] = rfl(p0[d]);
        q1[d] = rfl(p1[d]);
      }
    }
    lm0 = -1e30f;
    lm1 = -1e30f;
    {
      const float4* __restrict__ kt4 =
          (const float4*)krt + (size_t)h * 8 * N_TOK;
      for (int t = 0; t < NSLOT; t++) {
        const int m = tid + 256 * t;
        const int mc = (m < N_TOK) ? m : (N_TOK - 1);
        float4 kv[8];
#pragma unroll
        for (int g = 0; g < 8; g++) kv[g] = kt4[g * N_TOK + mc];
        float d0 = 0.f, d1 = 0.f;
#pragma unroll
        for (int g = 0; g < 8; g++) {
          d0 += q0[4 * g] * kv[g].x + q0[4 * g + 1] * kv[g].y +
                q0[4 * g + 2] * kv[g].z + q0[4 * g + 3] * kv[g].w;
          d1 += q1[4 * g] * kv[g].x + q1[4 * g + 1] * kv[g].y +
                q1[4 * g + 2] * kv[g].z + q1[4 * g + 3] * kv[g].w;
        }
        d0 *= SCALE;
        d1 *= SCALE;
        if (m >= N_TOK) { d0 = -1e30f; d1 = -1e30f; }
        sc0[t] = d0;
        sc1[t] = d1;
        lm0 = fmaxf(lm0, d0);
        lm1 = fmaxf(lm1, d1);
      }
    }
    const float M0r = block_max256(lm0, red);
    const float M1r = block_max256(lm1, red);
    ls0 = 0.f;
    ls1 = 0.f;
#pragma unroll
    for (int t = 0; t < NSLOT; t++) {
      const float e0 = expf(sc0[t] - M0r);
      const float e1 = expf(sc1[t] - M1r);
      sc0[t] = e0;
      sc1[t] = e1;
      ls0 += e0;
      ls1 += e1;
    }
    const float S0r = block_sum256(ls0, red);
    const float S1r = block_sum256(ls1, red);
    const float n0r = 0.5f / S0r, n1r = 0.5f / S1r;
#pragma unroll
    for (int t = 0; t < NSLOT; t++) {
      const int m = tid + 256 * t;
      if (m < N_TOK) {
        float a0 = s_attn[m] + sc0[t] * n0r;
        float a1 = s_attn[N_TOK + m] + sc1[t] * n1r;
        if (m >= b0 && m < b0 + 9 && m != i0) a0 = 0.f;
        if (m >= b1 && m < b1 + 9 && m != i1) a1 = 0.f;
        s_attn[m] = a0;
        s_attn[N_TOK + m] = a1;
        sim_row[m] += a0;
        sim_row[N_TOK + m] += a1;
      }
    }

    // ================= phase V: vn cosine (raw) =================
    {
#pragma unroll
      for (int d = 0; d < HD; d++) {
        const int g = d >> 2, comp = d & 3;
        q0[d] = rfl(vnt[((size_t)(h * 8 + g) * N_TOK + i0) * 4 + comp]);
        q1[d] = rfl(vnt[((size_t)(h * 8 + g) * N_TOK + i1) * 4 + comp]);
      }
      const float4* __restrict__ kt4 =
          (const float4*)vnt + (size_t)h * 8 * N_TOK;
      for (int t = 0; t < NSLOT; t++) {
        const int m = tid + 256 * t;
        const int mc = (m < N_TOK) ? m : (N_TOK - 1);
        float4 kv[8];
#pragma unroll
        for (int g = 0; g < 8; g++) kv[g] = kt4[g * N_TOK + mc];
        float d0 = 0.f, d1 = 0.f;
#pragma unroll
        for (int g = 0; g < 8; g++) {
          d0 += q0[4 * g] * kv[g].x + q0[4 * g + 1] * kv[g].y +
                q0[4 * g + 2] * kv[g].z + q0[4 * g + 3] * kv[g].w;
          d1 += q1[4 * g] * kv[g].x + q1[4 * g + 1] * kv[g].y +
                q1[4 * g + 2] * kv[g].z + q1[4 * g + 3] * kv[g].w;
        }
        if (m < N_TOK) {
          raw_row[m] += d0;
          raw_row[N_TOK + m] += d1;
        }
      }
    }
    __syncthreads();  // s_attn final for this head

    // ================= attn @ V =================
    {
      const int g2 = tid & 7, slice = tid >> 3;
      const int m0 = slice * 63;
      const int mend = (m0 + 63 < N_TOK) ? (m0 + 63) : N_TOK;
      float4 a0acc = {0.f, 0.f, 0.f, 0.f}, a1acc = {0.f, 0.f, 0.f, 0.f};
      const float4* __restrict__ v4 =
          (const float4*)v_rm + (size_t)h * N_TOK * 8;
      for (int m = m0; m < mend; m++) {
        const float4 vv = v4[m * 8 + g2];
        const float a0 = s_attn[m];
        const float a1 = s_attn[N_TOK + m];
        a0acc.x += a0 * vv.x; a0acc.y += a0 * vv.y;
        a0acc.z += a0 * vv.z; a0acc.w += a0 * vv.w;
        a1acc.x += a1 * vv.x; a1acc.y += a1 * vv.y;
        a1acc.z += a1 * vv.z; a1acc.w += a1 * vv.w;
      }
      part4[slice][0][g2] = a0acc;
      part4[slice][1][g2] = a1acc;
    }
    __syncthreads();
    if (tid < 16) {
      const int q = tid >> 3, g = tid & 7;
      float4 s = {0.f, 0.f, 0.f, 0.f};
#pragma unroll 8
      for (int sl = 0; sl < 32; sl++) {
        const float4 p = part4[sl][q][g];
        s.x += p.x; s.y += p.y; s.z += p.z; s.w += p.w;
      }
      const int irow = q ? i1 : i0;
      *(float4*)(out_x + (size_t)irow * 512 + h * 32 + 4 * g) = s;
    } else if (tid >= 64 && tid < 128) {
      const int q = (tid - 64) >> 5, d = (tid - 64) & 31;
      const int irow = q ? i1 : i0;
      out_x[(size_t)irow * 512 + 256 + h * 32 + d] =
          v_rm[((size_t)h * N_TOK + irow) * HD + d];
    }
    __syncthreads();  // protect s_attn/part4 before next head
  }

  // ================= sim_round2 epilogue =================
  for (int q = 0; q < 2; q++) {
    const int irow = q ? i1 : i0;
    float* __restrict__ srow = sim_row + q * N_TOK;
    float* __restrict__ rrow = raw_row + q * N_TOK;

    float lm = -1e30f;
    for (int m = tid; m < N_TOK; m += 256) lm = fmaxf(lm, srow[m] * 0.125f);
    const float M = block_max256(lm, red);

    float ls = 0.f;
    for (int m = tid; m < N_TOK; m += 256) {
      const float e = expf(srow[m] * 0.125f - M);
      srow[m] = e;
      ls += e;
    }
    const float S = block_sum256(ls, red);
    const float invS = 1.0f / S;

    float lms = 0.f;
    for (int m = tid; m < N_TOK; m += 256) {
      const float p = srow[m] * invS;
      const float mp = (rrow[m] * 0.125f > SIM_TH) ? p : 0.f;
      srow[m] = mp;
      lms += mp;
    }
    const float MS = block_sum256(lms, red);
    const float invMS = 1.0f / (MS + EPSF);

    for (int m = tid; m < N_TOK; m += 256) {
      out_sim[(size_t)irow * N_TOK + m] = srow[m] * invMS;
    }
  }
}

// ---------------------------------------------------------------------------
extern "C" void kernel_launch(void* const* d_in, const int* in_sizes, int n_in,
                              void* d_out, int out_size, void* d_ws,
                              size_t ws_size, hipStream_t stream) {
  const float* x_cls = (const float*)d_in[0];
  const float* x_reg = (const float*)d_in[1];
  const float* W_cls = (const float*)d_in[2];
  const float* W_reg = (const float*)d_in[3];

  float* ws = (float*)d_ws;
  const size_t seg = (size_t)NH * N_TOK * HD;  // 512000 floats
  float* qn_cls = ws;
  float* qn_reg = qn_cls + seg;
  float* kct = qn_reg + seg;
  float* krt = kct + seg;
  float* vnt = krt + seg;
  float* v_rm = vnt + seg;

  dim3 g1(500, 2);
  qkv_norm_kernel<<<g1, 256, 0, stream>>>(x_cls, x_reg, W_cls, W_reg, qn_cls,
                                          qn_reg, kct, krt, vnt, v_rm);

  float* out_x = (float*)d_out;                  // [2000, 512]
  float* out_sim = out_x + (size_t)N_TOK * 512;  // [2000, 2000]
  attn2_kernel<<<1000, 256, 0, stream>>>(qn_cls, qn_reg, kct, krt, vnt, v_rm,
                                         out_x, out_sim);
}